// Round 1
// 71.399 us; speedup vs baseline: 1.1839x; 1.1839x over previous
//
#include <hip/hip_runtime.h>
#include <math.h>

// Problem constants (match reference setup_inputs)
#define A_CNT   256
#define N_VIEW  20
#define D_DIM   256
#define NCLS    19
#define N_ROWS  (A_CNT * N_VIEW)   // 5120
#define N_TILES 320                // N_ROWS / 16 rows per MFMA tile

#define TEMP      0.1
#define BASE_TEMP 0.07

// MFMA fragment types (guide §3: 8 bf16 = 4 VGPRs, 4 f32 accum)
typedef short  s16x8 __attribute__((ext_vector_type(8)));
typedef float  f32x4 __attribute__((ext_vector_type(4)));

// ---------------------------------------------------------------------------
// Single fused kernel. One wave per 16-row tile of contrast_feature
// (rows n = v*256 + a; tile = 16 consecutive anchors at one view).
// Logits via v_mfma_f32_16x16x32_bf16:
//   A: 16 feature rows, lane layout row=lane&15, k=(lane>>4)*8+e (bf16x8)
//   B: proto is [19][256] = B^T (N x K) -> same per-lane layout, classes
//      padded to 32 with zero frags (two 16-wide N tiles).
//   C/D: col=lane&15, row=(lane>>4)*4+reg  [m89-verified]
// Epilogue in f32 (hardware exp/log), per-row reductions over the 16-lane
// group that owns the row. Final: f64 atomic accumulate + completion counter;
// last block writes the scalar.
// ---------------------------------------------------------------------------
__global__ __launch_bounds__(64) void pcl_fused(
        const unsigned short* __restrict__ feats,   // [A, N_VIEW, D] bf16 bits
        const unsigned short* __restrict__ proto,   // [NCLS, D] bf16 bits
        const int*   __restrict__ labels,           // [A]
        const int*   __restrict__ btch,             // [A]
        double* __restrict__ gsum,                  // ws: zeroed by memset
        int*    __restrict__ gcnt,                  // ws: zeroed by memset
        float*  __restrict__ out) {
    __shared__ int sCnt[32];      // per-class counts, zero-padded to 32
    __shared__ int sCb[40];       // per-(class,btch) counts
    __shared__ int sLab[A_CNT];
    __shared__ int sBt[A_CNT];

    const int t = threadIdx.x;    // 0..63 (one wave)

    // ---- per-block class counts (redundant per block; L2-hot, trivial) ----
    if (t < 32) sCnt[t] = 0;
    if (t < 40) sCb[t]  = 0;
    __syncthreads();
    for (int i = t; i < A_CNT; i += 64) {
        const int L = labels[i];
        const int B = btch[i];
        sLab[i] = L;
        sBt[i]  = B;
        atomicAdd(&sCnt[L], 1);
        atomicAdd(&sCb[L * 2 + B], 1);
    }
    __syncthreads();

    // ---- tile geometry ----
    const int tile = blockIdx.x;          // 0..319
    const int v    = tile >> 4;           // view of this tile's 16 rows
    const int a0   = (tile & 15) << 4;    // first anchor of tile
    const int lo   = t & 15;
    const int hi   = t >> 4;

    // ---- A fragments: feats row (a0+lo, v), k = s*32 + hi*8 ----
    const unsigned short* fbase =
        feats + ((size_t)((a0 + lo) * N_VIEW + v)) * D_DIM + hi * 8;
    s16x8 af[8];
#pragma unroll
    for (int s = 0; s < 8; ++s)
        af[s] = *(const s16x8*)(fbase + s * 32);

    // ---- B fragments: classes lo (tile0) and 16+lo (tile1, zero-padded) ----
    const unsigned short* pbase0 = proto + lo * D_DIM + hi * 8;
    s16x8 bf0[8], bf1[8];
#pragma unroll
    for (int s = 0; s < 8; ++s)
        bf0[s] = *(const s16x8*)(pbase0 + s * 32);
    if (16 + lo < NCLS) {
        const unsigned short* pbase1 = proto + (16 + lo) * D_DIM + hi * 8;
#pragma unroll
        for (int s = 0; s < 8; ++s)
            bf1[s] = *(const s16x8*)(pbase1 + s * 32);
    } else {
        const s16x8 z = {0, 0, 0, 0, 0, 0, 0, 0};
#pragma unroll
        for (int s = 0; s < 8; ++s)
            bf1[s] = z;
    }

    // ---- 16 MFMAs: 16 rows x 32 classes over K=256 ----
    f32x4 acc0 = {0.f, 0.f, 0.f, 0.f};
    f32x4 acc1 = {0.f, 0.f, 0.f, 0.f};
#pragma unroll
    for (int s = 0; s < 8; ++s) {
        acc0 = __builtin_amdgcn_mfma_f32_16x16x32_bf16(af[s], bf0[s], acc0, 0, 0, 0);
        acc1 = __builtin_amdgcn_mfma_f32_16x16x32_bf16(af[s], bf1[s], acc1, 0, 0, 0);
    }

    // ---- epilogue: 4 rows per 16-lane group ----
    const float invT = (float)(1.0 / TEMP);
    const int   cn0  = sCnt[lo];
    const int   cn1  = sCnt[16 + lo];   // 0 for padded classes
    float waveacc = 0.f;

#pragma unroll
    for (int r = 0; r < 4; ++r) {
        const int aa = a0 + hi * 4 + r;       // this output row's anchor
        const int ca = sLab[aa];
        const int ba = sBt[aa];
        const float d0 = acc0[r] * invT;      // logit of class lo
        const float d1 = acc1[r] * invT;      // logit of class 16+lo

        // row max over present classes
        float mx = fmaxf(cn0 > 0 ? d0 : -__builtin_inff(),
                         cn1 > 0 ? d1 : -__builtin_inff());
#pragma unroll
        for (int o = 1; o <= 8; o <<= 1)
            mx = fmaxf(mx, __shfl_xor(mx, o, 64));

        // negatives sum (classes != ca, weighted by counts) and d[ca] pick
        float e = (cn0 > 0 && lo != ca) ? (float)cn0 * __expf(d0 - mx) : 0.f;
        if (cn1 > 0 && (16 + lo) != ca) e += (float)cn1 * __expf(d1 - mx);
        float dca = (lo == ca) ? d0 : (((16 + lo) == ca) ? d1 : 0.f);
#pragma unroll
        for (int o = 1; o <= 8; o <<= 1) {
            e   += __shfl_xor(e, o, 64);
            dca += __shfl_xor(dca, o, 64);
        }

        const float S    = (float)N_VIEW * e;                 // 20 * sum
        const float eca  = __expf(dca - mx);
        const float lp   = (dca - mx) - __logf(eca + S);
        const float posN = (float)N_VIEW * (float)sCb[ca * 2 + (1 - ba)];
        if (lo == 0)                       // one lane per group accumulates
            waveacc += posN * lp / (posN + 1e-8f);
    }

    // ---- wave total (only lanes with lo==0 carry nonzero) ----
    waveacc += __shfl_xor(waveacc, 16, 64);
    waveacc += __shfl_xor(waveacc, 32, 64);

    if (t == 0) {
        atomicAdd(gsum, (double)waveacc);
        __threadfence();
        const int old = atomicAdd(gcnt, 1);
        if (old == N_TILES - 1) {          // last block finalizes
            __threadfence();
            const double s    = atomicAdd(gsum, 0.0);   // read current total
            const double loss = -(TEMP / BASE_TEMP) * s / (double)N_ROWS;
            out[0] = isnan(loss) ? 0.0f : (float)loss;
        }
    }
}

extern "C" void kernel_launch(void* const* d_in, const int* in_sizes, int n_in,
                              void* d_out, int out_size, void* d_ws, size_t ws_size,
                              hipStream_t stream) {
    const unsigned short* feats  = (const unsigned short*)d_in[0]; // bf16 [256,20,256]
    const unsigned short* proto  = (const unsigned short*)d_in[1]; // bf16 [19,256]
    const int*            labels = (const int*)d_in[2];            // [256] i32
    const int*            btch   = (const int*)d_in[3];            // [256] i32
    float* out = (float*)d_out;                                    // f32 scalar

    double* gsum = (double*)d_ws;                // 8 B
    int*    gcnt = (int*)((char*)d_ws + 8);      // 4 B

    hipMemsetAsync(d_ws, 0, 16, stream);         // graph-capturable memset node
    pcl_fused<<<N_TILES, 64, 0, stream>>>(feats, proto, labels, btch,
                                          gsum, gcnt, out);
}

// Round 2
// 65.591 us; speedup vs baseline: 1.2887x; 1.0886x over previous
//
#include <hip/hip_runtime.h>
#include <math.h>

// Problem constants (match reference setup_inputs)
#define A_CNT   256
#define N_VIEW  20
#define D_DIM   256
#define NCLS    19
#define N_ROWS  (A_CNT * N_VIEW)   // 5120
#define N_TILES 320                // N_ROWS / 16 rows per MFMA tile
#define BLOCKS  80                 // 4 waves/block, 1 tile/wave
#define WAVES   4

#define TEMP      0.1
#define BASE_TEMP 0.07

// MFMA fragment types (guide §3: 8 bf16 = 4 VGPRs, 4 f32 accum)
typedef short  s16x8 __attribute__((ext_vector_type(8)));
typedef float  f32x4 __attribute__((ext_vector_type(4)));

// ---------------------------------------------------------------------------
// Fused kernel, operand-swapped MFMA:
//   D = A(proto: classes as M) x B(feats rows as N)
//   A-frag: lane holds proto class (lane&15), k-chunk (lane>>4)*8  [8 bf16]
//   B-frag: lane holds feats row a0+(lane&15), k-chunk (lane>>4)*8 [8 bf16]
//   C/D (m89-verified): col = lane&15 = FEAT ROW, row = (lane>>4)*4+reg = CLASS
// => each lane owns feat-row a0+lo and classes {hi*4+r} (acc0) and
//    {16+hi*4+r} (acc1, classes 16..18 real, rest zero-padded).
// Softmax over classes = local 8-elem reduce + shfl_xor(16) + shfl_xor(32).
// Grid: 80 blocks x 256 threads; wave w of block b handles tile 4b+w.
// ---------------------------------------------------------------------------
__global__ __launch_bounds__(256) void pcl_fused(
        const unsigned short* __restrict__ feats,   // [A, N_VIEW, D] bf16 bits
        const unsigned short* __restrict__ proto,   // [NCLS, D] bf16 bits
        const int*   __restrict__ labels,           // [A]
        const int*   __restrict__ btch,             // [A]
        double* __restrict__ gsum,                  // ws: zeroed by memset
        int*    __restrict__ gcnt,                  // ws: zeroed by memset
        float*  __restrict__ out) {
    __shared__ int   sCnt[32];      // per-class counts, zero-padded to 32
    __shared__ int   sCb[40];       // per-(class,btch) counts
    __shared__ int   sLab[A_CNT];
    __shared__ int   sBt[A_CNT];
    __shared__ float sRed[WAVES];

    const int t = threadIdx.x;      // 0..255

    // ---- prep: one anchor per thread (amortized over 4 waves) ----
    if (t < 32) sCnt[t] = 0;
    if (t < 40) sCb[t]  = 0;
    __syncthreads();
    {
        const int L = labels[t];    // t < 256 == A_CNT exactly
        const int B = btch[t];
        sLab[t] = L;
        sBt[t]  = B;
        atomicAdd(&sCnt[L], 1);
        atomicAdd(&sCb[L * 2 + B], 1);
    }
    __syncthreads();

    // ---- tile geometry ----
    const int w    = t >> 6;              // wave 0..3
    const int l    = t & 63;
    const int lo   = l & 15;
    const int hi   = l >> 4;
    const int tile = blockIdx.x * WAVES + w;   // 0..319
    const int v    = tile >> 4;                // view
    const int a0   = (tile & 15) << 4;         // first anchor of tile

    // ---- B fragments: feats row (a0+lo, v), k = s*32 + hi*8 ----
    const unsigned short* fbase =
        feats + ((size_t)((a0 + lo) * N_VIEW + v)) * D_DIM + hi * 8;
    s16x8 bfeat[8];
#pragma unroll
    for (int s = 0; s < 8; ++s)
        bfeat[s] = *(const s16x8*)(fbase + s * 32);

    // ---- A fragments: proto classes lo (tile0) and 16+lo (tile1, padded) ----
    const unsigned short* pbase0 = proto + lo * D_DIM + hi * 8;
    s16x8 ap0[8], ap1[8];
#pragma unroll
    for (int s = 0; s < 8; ++s)
        ap0[s] = *(const s16x8*)(pbase0 + s * 32);
    if (16 + lo < NCLS) {
        const unsigned short* pbase1 = proto + (16 + lo) * D_DIM + hi * 8;
#pragma unroll
        for (int s = 0; s < 8; ++s)
            ap1[s] = *(const s16x8*)(pbase1 + s * 32);
    } else {
        const s16x8 z = {0, 0, 0, 0, 0, 0, 0, 0};
#pragma unroll
        for (int s = 0; s < 8; ++s)
            ap1[s] = z;
    }

    // ---- 16 MFMAs: (32-pad classes) x (16 rows) over K=256 ----
    f32x4 acc0 = {0.f, 0.f, 0.f, 0.f};
    f32x4 acc1 = {0.f, 0.f, 0.f, 0.f};
#pragma unroll
    for (int s = 0; s < 8; ++s) {
        acc0 = __builtin_amdgcn_mfma_f32_16x16x32_bf16(ap0[s], bfeat[s], acc0, 0, 0, 0);
        acc1 = __builtin_amdgcn_mfma_f32_16x16x32_bf16(ap1[s], bfeat[s], acc1, 0, 0, 0);
    }

    // ---- epilogue: lane owns feat-row a0+lo, classes hi*4+r / 16+hi*4+r ----
    const float invT = (float)(1.0 / TEMP);
    const int   aa   = a0 + lo;           // this lane's anchor
    const int   ca   = sLab[aa];
    const int   ba   = sBt[aa];

    float d0[4], d1[4];
    int   cn0[4], cn1[4];
#pragma unroll
    for (int r = 0; r < 4; ++r) {
        d0[r]  = acc0[r] * invT;
        d1[r]  = acc1[r] * invT;
        cn0[r] = sCnt[hi * 4 + r];        // group-uniform LDS (broadcast)
        cn1[r] = sCnt[16 + hi * 4 + r];   // 0 for padded classes
    }

    // row max over present classes
    float mloc = -__builtin_inff();
#pragma unroll
    for (int r = 0; r < 4; ++r) {
        if (cn0[r] > 0) mloc = fmaxf(mloc, d0[r]);
        if (cn1[r] > 0) mloc = fmaxf(mloc, d1[r]);
    }
    float mx = fmaxf(mloc, __shfl_xor(mloc, 16, 64));
    mx = fmaxf(mx, __shfl_xor(mx, 32, 64));

    // negatives sum (count-weighted) and d[ca] pick
    float eloc = 0.f, dloc = 0.f;
#pragma unroll
    for (int r = 0; r < 4; ++r) {
        const int c0 = hi * 4 + r;
        if (cn0[r] > 0 && c0 != ca) eloc += (float)cn0[r] * __expf(d0[r] - mx);
        if (c0 == ca)               dloc += d0[r];
        const int c1 = 16 + hi * 4 + r;
        if (cn1[r] > 0 && c1 != ca) eloc += (float)cn1[r] * __expf(d1[r] - mx);
        if (c1 == ca)               dloc += d1[r];
    }
    float e = eloc + __shfl_xor(eloc, 16, 64);
    e += __shfl_xor(e, 32, 64);
    float dca = dloc + __shfl_xor(dloc, 16, 64);
    dca += __shfl_xor(dca, 32, 64);

    const float S    = (float)N_VIEW * e;               // 20 * weighted sum
    const float md   = dca - mx;                        // <= 0
    const float lp   = md - __logf(__expf(md) + S);
    const float posN = (float)N_VIEW * (float)sCb[ca * 2 + (1 - ba)];
    const float mlp  = posN * lp / (posN + 1e-8f);

    // one lane per feat-row contributes; wave-reduce all 64 lanes
    float val = (hi == 0) ? mlp : 0.f;
#pragma unroll
    for (int o = 1; o <= 32; o <<= 1) val += __shfl_xor(val, o, 64);

    if (l == 0) sRed[w] = val;
    __syncthreads();

    if (t == 0) {
        const double bs = (double)sRed[0] + (double)sRed[1] +
                          (double)sRed[2] + (double)sRed[3];
        atomicAdd(gsum, bs);
        __threadfence();
        const int old = atomicAdd(gcnt, 1);
        if (old == BLOCKS - 1) {           // last block finalizes
            __threadfence();
            const double s    = atomicAdd(gsum, 0.0);   // read current total
            const double loss = -(TEMP / BASE_TEMP) * s / (double)N_ROWS;
            out[0] = isnan(loss) ? 0.0f : (float)loss;
        }
    }
}

extern "C" void kernel_launch(void* const* d_in, const int* in_sizes, int n_in,
                              void* d_out, int out_size, void* d_ws, size_t ws_size,
                              hipStream_t stream) {
    const unsigned short* feats  = (const unsigned short*)d_in[0]; // bf16 [256,20,256]
    const unsigned short* proto  = (const unsigned short*)d_in[1]; // bf16 [19,256]
    const int*            labels = (const int*)d_in[2];            // [256] i32
    const int*            btch   = (const int*)d_in[3];            // [256] i32
    float* out = (float*)d_out;                                    // f32 scalar

    double* gsum = (double*)d_ws;                // 8 B
    int*    gcnt = (int*)((char*)d_ws + 8);      // 4 B

    hipMemsetAsync(d_ws, 0, 16, stream);         // tiny graph-capturable node
    pcl_fused<<<BLOCKS, 256, 0, stream>>>(feats, proto, labels, btch,
                                          gsum, gcnt, out);
}